// Round 21
// baseline (154.628 us; speedup 1.0000x reference)
//
#include <hip/hip_runtime.h>
#include <math.h>

#define CIN   32
#define COUT  64
#define DD    20
#define PD    22        // padded dim
#define PSP   (PD*PD*PD)   // 10648
#define NSP   8000      // 20*20*20
#define BB    2
#define EPSN  1e-5f
#define SLOPE 0.01f
#define LOG2E 1.4426950408889634f

#define NT     250              // 32-row k/q tiles per batch
#define SPLITS 8                // 1008 blocks ~= one residency round
#define QUADS  63               // ceil(250/4) q-tiles, 4 per block

#define COG 8                   // conv: output channels per thread (8 -> halves x re-read; L2-BW bound)
#define OG  4                   // qkv: output channels per thread (16 o-groups)

typedef float  f32x16 __attribute__((ext_vector_type(16)));
typedef short  short8 __attribute__((ext_vector_type(8)));

__device__ __forceinline__ unsigned short f2bf_rne(float x) {
    unsigned u = __float_as_uint(x);
    unsigned r = (u + 0x7FFFu + ((u >> 16) & 1u)) >> 16;
    return (unsigned short)r;
}
__device__ __forceinline__ float bf2f(unsigned short h) {
    return __uint_as_float(((unsigned)h) << 16);
}
__device__ __forceinline__ short8 ld_frag(const unsigned short* p) {
    uint4 t = *reinterpret_cast<const uint4*>(p);
    return __builtin_bit_cast(short8, t);
}
// async global->LDS, 16B per lane; LDS dest is wave-uniform base + lane*16
__device__ __forceinline__ void gload_lds16(const void* gsrc, void* ldst) {
    typedef __attribute__((address_space(1))) const unsigned int GU;
    typedef __attribute__((address_space(3))) unsigned int LU;
    __builtin_amdgcn_global_load_lds((GU*)gsrc, (LU*)ldst, 16, 0, 0);
}
// raw 2^x (v_exp_f32); inputs here are <= 0 and well in range
__device__ __forceinline__ float exp2_fast(float x) {
    float r;
    asm("v_exp_f32 %0, %1" : "=v"(r) : "v"(x));
    return r;
}
// full-wave sum via xor-shuffle butterfly (deterministic)
__device__ __forceinline__ float wsum(float x) {
    #pragma unroll
    for (int off = 1; off < 64; off <<= 1) x += __shfl_xor(x, off, 64);
    return x;
}

// ---------------- zero-pad x into [B][CIN][22][22][22] ----------------
__global__ void pad_k(const float* __restrict__ x, float* __restrict__ xp) {
    int idx = blockIdx.x * blockDim.x + threadIdx.x;
    if (idx >= BB * CIN * PSP) return;
    int pw = idx % PD;
    int ph = (idx / PD) % PD;
    int pd = (idx / (PD * PD)) % PD;
    int bc = idx / PSP;
    float v = 0.f;
    if (pw >= 1 && pw <= DD && ph >= 1 && ph <= DD && pd >= 1 && pd <= DD)
        v = x[(size_t)bc * NSP + ((size_t)(pd - 1) * DD + (ph - 1)) * DD + (pw - 1)];
    xp[idx] = v;
}

// ---------------- Conv3d k=3 s=1 SAME + bias + fused instance-norm partials ----------------
// COG=8: 8 co-groups -> x re-read 8x (was 16x) -> halves L2 traffic (conv is L2-BW bound:
// 917MB/25us = 36.7 TB/s = the L2 ceiling at COG=4).
__global__ __launch_bounds__(256) void conv3d_k(const float* __restrict__ xp,
                                                const float* __restrict__ w,
                                                const float* __restrict__ bias,
                                                float* __restrict__ y,
                                                float2* __restrict__ part) {
    int blk = blockIdx.x;
    int vb  = blk & 31;
    int cg  = (blk >> 5) & 7;       // uniform co-group (of 8)
    int b   = blk >> 8;
    int vox = vb * 256 + threadIdx.x;
    bool valid = vox < NSP;
    int v  = valid ? vox : 0;
    int w_ = v % DD;
    int h_ = (v / DD) % DD;
    int d_ = v / (DD * DD);
    int pvox = ((d_ + 1) * PD + (h_ + 1)) * PD + (w_ + 1);
    const float* xb = xp + (size_t)b * CIN * PSP + pvox;

    float acc[COG];
    #pragma unroll
    for (int j = 0; j < COG; ++j) acc[j] = 0.f;

    for (int ci = 0; ci < CIN; ++ci) {
        const float* xc = xb + (size_t)ci * PSP;
        float xv[27];
        #pragma unroll
        for (int kd = 0; kd < 3; ++kd)
            #pragma unroll
            for (int kh = 0; kh < 3; ++kh)
                #pragma unroll
                for (int kw = 0; kw < 3; ++kw)
                    xv[(kd * 3 + kh) * 3 + kw] =
                        xc[(kd - 1) * (PD * PD) + (kh - 1) * PD + (kw - 1)];
        #pragma unroll
        for (int j = 0; j < COG; ++j) {
            int co = cg * COG + j;                       // uniform
            const float* wr = w + ((size_t)co * CIN + ci) * 27;
            float a = acc[j];
            #pragma unroll
            for (int t = 0; t < 27; ++t) a += xv[t] * wr[t];
            acc[j] = a;
        }
    }

    __shared__ float2 wred[4][COG];
    int wv = threadIdx.x >> 6;
    int ln = threadIdx.x & 63;
    #pragma unroll
    for (int j = 0; j < COG; ++j) {
        int co = cg * COG + j;
        float val = valid ? acc[j] + bias[co] : 0.f;
        if (valid) y[((size_t)b * COUT + co) * NSP + vox] = val;
        float s  = wsum(val);
        float ss = wsum(val * val);
        if (ln == 0) wred[wv][j] = make_float2(s, ss);
    }
    __syncthreads();
    if (threadIdx.x < COG) {
        int j = threadIdx.x;
        float s = 0.f, ss = 0.f;
        #pragma unroll
        for (int w2 = 0; w2 < 4; ++w2) { s += wred[w2][j].x; ss += wred[w2][j].y; }
        part[((size_t)(b * COUT + cg * COG + j)) * 32 + vb] = make_float2(s, ss);
    }
}

// ---------------- QKV projections (stats-finalize + norm + LeakyReLU fused) ----------------
// Q (single bf16, scaled by LOG2E), K (hi): [b][tile][c(4)][half(2)][row(32)][e(8)]
// V: [b][tile][Y(2)][X(2)][half(2)][row(32)][e(8)]
// OG=4: 16 o-groups -> 1024 blocks (4 waves/SIMD).  channel = og*4 + j
__global__ __launch_bounds__(256) void qkv_k(const float* __restrict__ yraw,
                      const float2* __restrict__ part,
                      const float* __restrict__ gamma, const float* __restrict__ beta,
                      const float* __restrict__ wq, const float* __restrict__ bq,
                      const float* __restrict__ wk, const float* __restrict__ bk,
                      const float* __restrict__ wv, const float* __restrict__ bv,
                      unsigned short* __restrict__ Qfh,
                      unsigned short* __restrict__ Kfh,
                      unsigned short* __restrict__ Vf) {
    int blk = blockIdx.x;
    int vb  = blk & 31;
    int og  = (blk >> 5) & 15;      // uniform o-group (of 4 channels)
    int b   = blk >> 9;
    int n   = vb * 256 + threadIdx.x;
    bool valid = n < NSP;
    int nn  = valid ? n : 0;
    const float* fb = yraw + (size_t)b * COUT * NSP + nn;

    // finalize instance-norm stats (deterministic 32-way chunk sum per channel)
    __shared__ float smean[COUT], srstd[COUT];
    if (threadIdx.x < COUT) {
        int c = threadIdx.x;
        float s = 0.f, ss = 0.f;
        #pragma unroll 8
        for (int ch = 0; ch < 32; ++ch) {
            float2 p = part[(size_t)(b * COUT + c) * 32 + ch];
            s += p.x; ss += p.y;
        }
        float mean = s * (1.f / NSP);
        smean[c] = mean;
        srstd[c] = rsqrtf(ss * (1.f / NSP) - mean * mean + EPSN);
    }
    __syncthreads();

    float aq[OG], ak[OG], av[OG];
    #pragma unroll
    for (int j = 0; j < OG; ++j) {
        int o = og * OG + j;
        aq[j] = bq[o]; ak[j] = bk[o]; av[j] = bv[o];
    }
    for (int c = 0; c < COUT; ++c) {
        float fc = (fb[(size_t)c * NSP] - smean[c]) * srstd[c] * gamma[c] + beta[c];
        fc = fc >= 0.f ? fc : SLOPE * fc;            // LeakyReLU fused
        #pragma unroll
        for (int j = 0; j < OG; ++j) {
            int o = og * OG + j;                         // uniform
            aq[j] += wq[o * COUT + c] * fc;
            ak[j] += wk[o * COUT + c] * fc;
            av[j] += wv[o * COUT + c] * fc;
        }
    }
    if (!valid) return;

    int t  = n >> 5;                // tile
    int kk = n & 31;                // row within tile
    unsigned short qh[OG], kh[OG];
    #pragma unroll
    for (int j = 0; j < OG; ++j) {
        qh[j] = f2bf_rne(aq[j] * LOG2E);   // log2-domain logits, single bf16
        kh[j] = f2bf_rne(ak[j]);
    }
    // Q/K store: channel ch = og*4+j -> c = og>>2, half = (og>>1)&1, e0 = (og&1)*4
    size_t qko = ((size_t)((b * NT + t) * 4 + (og >> 2)) * 2 + ((og >> 1) & 1)) * 256
               + kk * 8 + (og & 1) * 4;
    *reinterpret_cast<uint2*>(Qfh + qko) = *reinterpret_cast<const uint2*>(qh);
    *reinterpret_cast<uint2*>(Kfh + qko) = *reinterpret_cast<const uint2*>(kh);
    // V store: ch = og*4+j -> X = og>>3, row = (og&7)*4+j ; Y/hf/e from kk
    {
        int Y = kk >> 4, hf = (kk >> 3) & 1, e = kk & 7;
        size_t vbase = ((size_t)((b * NT + t) * 2 + Y) * 2 + (og >> 3)) * 512
                     + hf * 256 + e;
        #pragma unroll
        for (int j = 0; j < OG; ++j)
            Vf[vbase + ((og & 7) * 4 + j) * 8] = f2bf_rne(av[j]);
    }
}

// ---------------- flash attention pass 1: MFMA, pair-ILP (R15-proven structure) ----------------
__global__ __launch_bounds__(256, 4) void attn_pass1_mfma(
        const unsigned short* __restrict__ Qfh,
        const unsigned short* __restrict__ Kfh,
        const unsigned short* __restrict__ Vf,
        float* __restrict__ pm, float* __restrict__ pl, float* __restrict__ pacc) {
    int bid   = blockIdx.x;
    int split = bid / (BB * QUADS);         // split-major: co-resident share K/V window
    int rem   = bid % (BB * QUADS);
    int b     = rem / QUADS;
    int quad  = rem % QUADS;
    int wave  = threadIdx.x >> 6;
    int lane  = threadIdx.x & 63;
    int col   = lane & 31;
    int half  = lane >> 5;
    int qt    = quad * 4 + wave;
    bool qvalid = qt < NT;
    int qtc   = qvalid ? qt : NT - 1;
    int bNT   = b * NT;

    int tstart = (split * NT) / SPLITS;
    int tend   = ((split + 1) * NT) / SPLITS;
    int nkt    = tend - tstart;             // 31 or 32
    int npair  = nkt >> 1;
    int odd    = nkt & 1;

    __shared__ __align__(16) char ldsbuf[2][16384];  // pair: [Kh0 4K|V0 4K|Kh1 4K|V1 4K]

    short8 qfh[4];
    {
        const unsigned short* qp = Qfh + (size_t)(bNT + qtc) * 2048 + lane * 8;
        #pragma unroll
        for (int c = 0; c < 4; ++c) qfh[c] = ld_frag(qp + c * 512);
    }

    int wo = wave * 1024;
    int go = wo + lane * 16;

    auto STAGET = [&](int bufi, int slot, int tg) {
        size_t tb = (size_t)(bNT + tg) * 2048;
        char* l = &ldsbuf[bufi][slot * 8192];
        gload_lds16((const char*)(Kfh + tb) + go, l + wo);
        gload_lds16((const char*)(Vf  + tb) + go, l + 4096 + wo);
    };

    f32x16 oacc0 = {};
    f32x16 oacc1 = {};
    float m = -3e38f, lsum = 0.f;

    // softmax + PV for one tile (per-tile max update; R15-verified)
    auto SM_PV = [&](const f32x16& s, const unsigned short* lv) {
        float a0 = fmaxf(fmaxf(s[0],  s[1]),  s[2]);
        float a1 = fmaxf(fmaxf(s[3],  s[4]),  s[5]);
        float a2 = fmaxf(fmaxf(s[6],  s[7]),  s[8]);
        float a3 = fmaxf(fmaxf(s[9],  s[10]), s[11]);
        float a4 = fmaxf(fmaxf(s[12], s[13]), s[14]);
        float tmax = fmaxf(fmaxf(fmaxf(a0, a1), a2), fmaxf(fmaxf(a3, a4), s[15]));
        tmax = fmaxf(tmax, __shfl_xor(tmax, 32, 64));
        if (__any(tmax > m + 11.5f)) {
            float newm  = fmaxf(m, tmax);
            float scale = exp2_fast(m - newm);
            lsum *= scale;
            #pragma unroll
            for (int r = 0; r < 16; ++r) { oacc0[r] *= scale; oacc1[r] *= scale; }
            m = newm;
        }
        short8 pf0, pf1;
        float ls;
        {
            float p[8];
            #pragma unroll
            for (int r = 0; r < 8; ++r) p[r] = exp2_fast(s[r] - m);
            ls = ((p[0] + p[1]) + (p[2] + p[3])) + ((p[4] + p[5]) + (p[6] + p[7]));
            unsigned W[4], X[4];
            #pragma unroll
            for (int j = 0; j < 4; ++j)
                asm("v_cvt_pk_bf16_f32 %0, %1, %2" : "=v"(W[j]) : "v"(p[2 * j]), "v"(p[2 * j + 1]));
            #pragma unroll
            for (int j = 0; j < 4; ++j) X[j] = (unsigned)__shfl_xor((int)W[j], 32, 64);
            uint4 u = half ? make_uint4(X[2], X[3], W[2], W[3])
                           : make_uint4(W[0], W[1], X[0], X[1]);
            pf0 = __builtin_bit_cast(short8, u);
        }
        {
            float p[8];
            #pragma unroll
            for (int r = 0; r < 8; ++r) p[r] = exp2_fast(s[r + 8] - m);
            ls += ((p[0] + p[1]) + (p[2] + p[3])) + ((p[4] + p[5]) + (p[6] + p[7]));
            unsigned W[4], X[4];
            #pragma unroll
            for (int j = 0; j < 4; ++j)
                asm("v_cvt_pk_bf16_f32 %0, %1, %2" : "=v"(W[j]) : "v"(p[2 * j]), "v"(p[2 * j + 1]));
            #pragma unroll
            for (int j = 0; j < 4; ++j) X[j] = (unsigned)__shfl_xor((int)W[j], 32, 64);
            uint4 u = half ? make_uint4(X[2], X[3], W[2], W[3])
                           : make_uint4(W[0], W[1], X[0], X[1]);
            pf1 = __builtin_bit_cast(short8, u);
        }
        lsum += ls;
        short8 v00 = ld_frag(lv + 0 * 512 + lane * 8);   // Y0 X0
        short8 v10 = ld_frag(lv + 1 * 512 + lane * 8);   // Y0 X1
        __builtin_amdgcn_s_setprio(1);
        oacc0 = __builtin_amdgcn_mfma_f32_32x32x16_bf16(v00, pf0, oacc0, 0, 0, 0);
        oacc1 = __builtin_amdgcn_mfma_f32_32x32x16_bf16(v10, pf0, oacc1, 0, 0, 0);
        __builtin_amdgcn_s_setprio(0);
        short8 v01 = ld_frag(lv + 2 * 512 + lane * 8);   // Y1 X0
        short8 v11 = ld_frag(lv + 3 * 512 + lane * 8);   // Y1 X1
        __builtin_amdgcn_s_setprio(1);
        oacc0 = __builtin_amdgcn_mfma_f32_32x32x16_bf16(v01, pf1, oacc0, 0, 0, 0);
        oacc1 = __builtin_amdgcn_mfma_f32_32x32x16_bf16(v11, pf1, oacc1, 0, 0, 0);
        __builtin_amdgcn_s_setprio(0);
    };

    STAGET(0, 0, tstart);
    STAGET(0, 1, tstart + 1);

    for (int p = 0; p < npair; ++p) {
        __syncthreads();             // drains own pair's stage; prev buffer now free
        int nb = (p + 1) & 1;
        if (p + 1 < npair) {
            STAGET(nb, 0, tstart + 2 * p + 2);
            STAGET(nb, 1, tstart + 2 * p + 3);
        } else if (odd) {
            STAGET(nb, 0, tstart + 2 * p + 2);
        }
        const unsigned short* base = (const unsigned short*)&ldsbuf[p & 1][0];
        const unsigned short* lk0 = base;
        const unsigned short* lv0 = base + 2048;
        const unsigned short* lk1 = base + 4096;
        const unsigned short* lv1 = base + 6144;

        f32x16 s0 = {}, s1 = {};
        __builtin_amdgcn_s_setprio(1);
        #pragma unroll
        for (int c = 0; c < 4; ++c) {
            short8 k0 = ld_frag(lk0 + c * 512 + lane * 8);
            s0 = __builtin_amdgcn_mfma_f32_32x32x16_bf16(k0, qfh[c], s0, 0, 0, 0);
        }
        #pragma unroll
        for (int c = 0; c < 4; ++c) {
            short8 k1 = ld_frag(lk1 + c * 512 + lane * 8);
            s1 = __builtin_amdgcn_mfma_f32_32x32x16_bf16(k1, qfh[c], s1, 0, 0, 0);
        }
        __builtin_amdgcn_s_setprio(0);

        SM_PV(s0, lv0);
        SM_PV(s1, lv1);
    }
    if (odd) {
        __syncthreads();
        const unsigned short* base = (const unsigned short*)&ldsbuf[npair & 1][0];
        f32x16 s0 = {};
        __builtin_amdgcn_s_setprio(1);
        #pragma unroll
        for (int c = 0; c < 4; ++c) {
            short8 k0 = ld_frag(base + c * 512 + lane * 8);
            s0 = __builtin_amdgcn_mfma_f32_32x32x16_bf16(k0, qfh[c], s0, 0, 0, 0);
        }
        __builtin_amdgcn_s_setprio(0);
        SM_PV(s0, base + 2048);
    }

    if (!qvalid) return;
    int q0 = qt * 32;
    float lfull = lsum + __shfl_xor(lsum, 32, 64);
    size_t base = (size_t)b * SPLITS + split;
    if (lane < 32) {
        pm[base * NSP + q0 + col] = m;     // log2-domain running max
        pl[base * NSP + q0 + col] = lfull;
    }
    float* pa = pacc + base * (size_t)(COUT * NSP) + q0 + col;
    #pragma unroll
    for (int r = 0; r < 16; ++r) {
        int crow = (r & 3) + 8 * (r >> 2) + 4 * half;
        pa[(size_t)crow * NSP]        = oacc0[r];
        pa[(size_t)(crow + 32) * NSP] = oacc1[r];
    }
}

// ---------------- combine split-K partials (log2-domain, float4-vectorized) ----------------
__global__ void attn_combine_k(const float* __restrict__ pm, const float* __restrict__ pl,
                               const float* __restrict__ pacc, float* __restrict__ out) {
    int idx = blockIdx.x * blockDim.x + threadIdx.x;   // over B*COUT*NSP/4
    const int N4 = NSP / 4;
    if (idx >= BB * COUT * N4) return;
    int n4 = idx % N4;
    int c  = (idx / N4) % COUT;
    int b  = idx / (N4 * COUT);
    int n  = n4 * 4;

    float4 M = make_float4(-1e30f, -1e30f, -1e30f, -1e30f);
    #pragma unroll
    for (int j = 0; j < SPLITS; ++j) {
        float4 v = *reinterpret_cast<const float4*>(&pm[((size_t)b * SPLITS + j) * NSP + n]);
        M.x = fmaxf(M.x, v.x); M.y = fmaxf(M.y, v.y);
        M.z = fmaxf(M.z, v.z); M.w = fmaxf(M.w, v.w);
    }
    float4 L = make_float4(0.f, 0.f, 0.f, 0.f);
    float4 O = make_float4(0.f, 0.f, 0.f, 0.f);
    #pragma unroll
    for (int j = 0; j < SPLITS; ++j) {
        size_t base = (size_t)b * SPLITS + j;
        float4 pmv = *reinterpret_cast<const float4*>(&pm[base * NSP + n]);
        float4 plv = *reinterpret_cast<const float4*>(&pl[base * NSP + n]);
        float4 pav = *reinterpret_cast<const float4*>(&pacc[(base * COUT + c) * NSP + n]);
        float4 wgt;
        wgt.x = exp2_fast(pmv.x - M.x); wgt.y = exp2_fast(pmv.y - M.y);
        wgt.z = exp2_fast(pmv.z - M.z); wgt.w = exp2_fast(pmv.w - M.w);
        L.x += plv.x * wgt.x; L.y += plv.y * wgt.y;
        L.z += plv.z * wgt.z; L.w += plv.w * wgt.w;
        O.x += pav.x * wgt.x; O.y += pav.y * wgt.y;
        O.z += pav.z * wgt.z; O.w += pav.w * wgt.w;
    }
    float4 r;
    r.x = O.x / L.x; r.y = O.y / L.y; r.z = O.z / L.z; r.w = O.w / L.w;
    *reinterpret_cast<float4*>(&out[((size_t)(b * COUT + c)) * NSP + n]) = r;
}

// ---------------- launch ----------------
extern "C" void kernel_launch(void* const* d_in, const int* in_sizes, int n_in,
                              void* d_out, int out_size, void* d_ws, size_t ws_size,
                              hipStream_t stream) {
    const float* x      = (const float*)d_in[0];
    const float* conv_w = (const float*)d_in[1];
    const float* conv_b = (const float*)d_in[2];
    const float* gamma  = (const float*)d_in[3];
    const float* beta   = (const float*)d_in[4];
    const float* wq     = (const float*)d_in[5];
    const float* bq     = (const float*)d_in[6];
    const float* wk     = (const float*)d_in[7];
    const float* bk     = (const float*)d_in[8];
    const float* wv     = (const float*)d_in[9];
    const float* bv     = (const float*)d_in[10];
    float* out = (float*)d_out;

    const int ELEMS = BB * COUT * NSP;      // 1,024,000
    char* w8 = (char*)d_ws;
    float*  y    = (float*)w8;                          // 4,096,000 B
    float2* part = (float2*)(w8 + 4096000);             // 128*32 float2 = 32,768 B
    unsigned short* Qfh = (unsigned short*)(w8 + 4128768);
    unsigned short* Kfh = Qfh + (size_t)ELEMS;          // each 2,048,000 B
    unsigned short* Vf  = Kfh + (size_t)ELEMS;
    float* pm   = (float*)(Vf + (size_t)ELEMS);
    float* pl   = pm + (size_t)BB * SPLITS * NSP;       // 512,000 B each
    float* pacc = pl + (size_t)BB * SPLITS * NSP;       // 32,768,000 B
    // xpad aliases pacc: xpad live only before conv3d_k; pacc only after qkv_k
    float* xpad = pacc;                                 // needs 2,725,888 B

    pad_k<<<(BB * CIN * PSP + 255) / 256, 256, 0, stream>>>(x, xpad);
    conv3d_k<<<BB * 8 * 32, 256, 0, stream>>>(xpad, conv_w, conv_b, y, part);
    qkv_k<<<BB * 16 * 32, 256, 0, stream>>>(y, part, gamma, beta,
                                            wq, bq, wk, bk, wv, bv,
                                            Qfh, Kfh, Vf);
    attn_pass1_mfma<<<SPLITS * BB * QUADS, 256, 0, stream>>>(Qfh, Kfh, Vf,
                                                             pm, pl, pacc);
    attn_combine_k<<<(BB * COUT * (NSP / 4) + 255) / 256, 256, 0, stream>>>(pm, pl, pacc, out);
}

// Round 22
// 128.142 us; speedup vs baseline: 1.2067x; 1.2067x over previous
//
#include <hip/hip_runtime.h>
#include <math.h>

#define CIN   32
#define COUT  64
#define DD    20
#define PD    22        // padded dim
#define PSP   (PD*PD*PD)   // 10648
#define NSP   8000      // 20*20*20
#define BB    2
#define EPSN  1e-5f
#define SLOPE 0.01f
#define LOG2E 1.4426950408889634f

#define NT     250              // 32-row k/q tiles per batch
#define SPLITS 8                // 1008 blocks ~= one residency round
#define QUADS  63               // ceil(250/4) q-tiles, 4 per block

#define COG 4                   // conv: output channels per thread (4 is the codegen sweet spot;
                                //       8 and unroll-pragmas both collapse VGPR to 36 and 3x the time)
#define OG  4                   // qkv: output channels per thread (16 o-groups)

typedef float  f32x16 __attribute__((ext_vector_type(16)));
typedef short  short8 __attribute__((ext_vector_type(8)));

__device__ __forceinline__ unsigned short f2bf_rne(float x) {
    unsigned u = __float_as_uint(x);
    unsigned r = (u + 0x7FFFu + ((u >> 16) & 1u)) >> 16;
    return (unsigned short)r;
}
__device__ __forceinline__ float bf2f(unsigned short h) {
    return __uint_as_float(((unsigned)h) << 16);
}
__device__ __forceinline__ short8 ld_frag(const unsigned short* p) {
    uint4 t = *reinterpret_cast<const uint4*>(p);
    return __builtin_bit_cast(short8, t);
}
// async global->LDS, 16B per lane; LDS dest is wave-uniform base + lane*16
__device__ __forceinline__ void gload_lds16(const void* gsrc, void* ldst) {
    typedef __attribute__((address_space(1))) const unsigned int GU;
    typedef __attribute__((address_space(3))) unsigned int LU;
    __builtin_amdgcn_global_load_lds((GU*)gsrc, (LU*)ldst, 16, 0, 0);
}
// raw 2^x (v_exp_f32); inputs here are <= 0 and well in range
__device__ __forceinline__ float exp2_fast(float x) {
    float r;
    asm("v_exp_f32 %0, %1" : "=v"(r) : "v"(x));
    return r;
}
// full-wave sum via xor-shuffle butterfly (deterministic)
__device__ __forceinline__ float wsum(float x) {
    #pragma unroll
    for (int off = 1; off < 64; off <<= 1) x += __shfl_xor(x, off, 64);
    return x;
}

// ---------------- zero-pad x into [B][CIN][22][22][22] ----------------
__global__ void pad_k(const float* __restrict__ x, float* __restrict__ xp) {
    int idx = blockIdx.x * blockDim.x + threadIdx.x;
    if (idx >= BB * CIN * PSP) return;
    int pw = idx % PD;
    int ph = (idx / PD) % PD;
    int pd = (idx / (PD * PD)) % PD;
    int bc = idx / PSP;
    float v = 0.f;
    if (pw >= 1 && pw <= DD && ph >= 1 && ph <= DD && pd >= 1 && pd <= DD)
        v = x[(size_t)bc * NSP + ((size_t)(pd - 1) * DD + (ph - 1)) * DD + (pw - 1)];
    xp[idx] = v;
}

// ---------------- Conv3d k=3 s=1 SAME + bias + fused instance-norm partials ----------------
// (no unroll pragma; COG=4 — both alternates break the compiler's load batching)
__global__ __launch_bounds__(256) void conv3d_k(const float* __restrict__ xp,
                                                const float* __restrict__ w,
                                                const float* __restrict__ bias,
                                                float* __restrict__ y,
                                                float2* __restrict__ part) {
    int blk = blockIdx.x;
    int vb  = blk & 31;
    int cg  = (blk >> 5) & 15;      // uniform co-group (of 4)
    int b   = blk >> 9;
    int vox = vb * 256 + threadIdx.x;
    bool valid = vox < NSP;
    int v  = valid ? vox : 0;
    int w_ = v % DD;
    int h_ = (v / DD) % DD;
    int d_ = v / (DD * DD);
    int pvox = ((d_ + 1) * PD + (h_ + 1)) * PD + (w_ + 1);
    const float* xb = xp + (size_t)b * CIN * PSP + pvox;

    float acc[COG];
    #pragma unroll
    for (int j = 0; j < COG; ++j) acc[j] = 0.f;

    for (int ci = 0; ci < CIN; ++ci) {
        const float* xc = xb + (size_t)ci * PSP;
        float xv[27];
        #pragma unroll
        for (int kd = 0; kd < 3; ++kd)
            #pragma unroll
            for (int kh = 0; kh < 3; ++kh)
                #pragma unroll
                for (int kw = 0; kw < 3; ++kw)
                    xv[(kd * 3 + kh) * 3 + kw] =
                        xc[(kd - 1) * (PD * PD) + (kh - 1) * PD + (kw - 1)];
        #pragma unroll
        for (int j = 0; j < COG; ++j) {
            int co = cg * COG + j;                       // uniform
            const float* wr = w + ((size_t)co * CIN + ci) * 27;
            float a = acc[j];
            #pragma unroll
            for (int t = 0; t < 27; ++t) a += xv[t] * wr[t];
            acc[j] = a;
        }
    }

    __shared__ float2 wred[4][COG];
    int wv = threadIdx.x >> 6;
    int ln = threadIdx.x & 63;
    #pragma unroll
    for (int j = 0; j < COG; ++j) {
        int co = cg * COG + j;
        float val = valid ? acc[j] + bias[co] : 0.f;
        if (valid) y[((size_t)b * COUT + co) * NSP + vox] = val;
        float s  = wsum(val);
        float ss = wsum(val * val);
        if (ln == 0) wred[wv][j] = make_float2(s, ss);
    }
    __syncthreads();
    if (threadIdx.x < COG) {
        int j = threadIdx.x;
        float s = 0.f, ss = 0.f;
        #pragma unroll
        for (int w2 = 0; w2 < 4; ++w2) { s += wred[w2][j].x; ss += wred[w2][j].y; }
        part[((size_t)(b * COUT + cg * COG + j)) * 32 + vb] = make_float2(s, ss);
    }
}

// ---------------- QKV projections (stats-finalize + norm + LeakyReLU fused) ----------------
// Q (single bf16, scaled by LOG2E), K (hi): [b][tile][c(4)][half(2)][row(32)][e(8)]
// V: [b][tile][Y(2)][X(2)][half(2)][row(32)][e(8)]
// OG=4: 16 o-groups -> 1024 blocks (4 waves/SIMD).  channel = og*4 + j
__global__ __launch_bounds__(256) void qkv_k(const float* __restrict__ yraw,
                      const float2* __restrict__ part,
                      const float* __restrict__ gamma, const float* __restrict__ beta,
                      const float* __restrict__ wq, const float* __restrict__ bq,
                      const float* __restrict__ wk, const float* __restrict__ bk,
                      const float* __restrict__ wv, const float* __restrict__ bv,
                      unsigned short* __restrict__ Qfh,
                      unsigned short* __restrict__ Kfh,
                      unsigned short* __restrict__ Vf) {
    int blk = blockIdx.x;
    int vb  = blk & 31;
    int og  = (blk >> 5) & 15;      // uniform o-group (of 4 channels)
    int b   = blk >> 9;
    int n   = vb * 256 + threadIdx.x;
    bool valid = n < NSP;
    int nn  = valid ? n : 0;
    const float* fb = yraw + (size_t)b * COUT * NSP + nn;

    // finalize instance-norm stats (deterministic 32-way chunk sum per channel)
    __shared__ float smean[COUT], srstd[COUT];
    if (threadIdx.x < COUT) {
        int c = threadIdx.x;
        float s = 0.f, ss = 0.f;
        #pragma unroll 8
        for (int ch = 0; ch < 32; ++ch) {
            float2 p = part[(size_t)(b * COUT + c) * 32 + ch];
            s += p.x; ss += p.y;
        }
        float mean = s * (1.f / NSP);
        smean[c] = mean;
        srstd[c] = rsqrtf(ss * (1.f / NSP) - mean * mean + EPSN);
    }
    __syncthreads();

    float aq[OG], ak[OG], av[OG];
    #pragma unroll
    for (int j = 0; j < OG; ++j) {
        int o = og * OG + j;
        aq[j] = bq[o]; ak[j] = bk[o]; av[j] = bv[o];
    }
    for (int c = 0; c < COUT; ++c) {
        float fc = (fb[(size_t)c * NSP] - smean[c]) * srstd[c] * gamma[c] + beta[c];
        fc = fc >= 0.f ? fc : SLOPE * fc;            // LeakyReLU fused
        #pragma unroll
        for (int j = 0; j < OG; ++j) {
            int o = og * OG + j;                         // uniform
            aq[j] += wq[o * COUT + c] * fc;
            ak[j] += wk[o * COUT + c] * fc;
            av[j] += wv[o * COUT + c] * fc;
        }
    }
    if (!valid) return;

    int t  = n >> 5;                // tile
    int kk = n & 31;                // row within tile
    unsigned short qh[OG], kh[OG];
    #pragma unroll
    for (int j = 0; j < OG; ++j) {
        qh[j] = f2bf_rne(aq[j] * LOG2E);   // log2-domain logits, single bf16
        kh[j] = f2bf_rne(ak[j]);
    }
    // Q/K store: channel ch = og*4+j -> c = og>>2, half = (og>>1)&1, e0 = (og&1)*4
    size_t qko = ((size_t)((b * NT + t) * 4 + (og >> 2)) * 2 + ((og >> 1) & 1)) * 256
               + kk * 8 + (og & 1) * 4;
    *reinterpret_cast<uint2*>(Qfh + qko) = *reinterpret_cast<const uint2*>(qh);
    *reinterpret_cast<uint2*>(Kfh + qko) = *reinterpret_cast<const uint2*>(kh);
    // V store: ch = og*4+j -> X = og>>3, row = (og&7)*4+j ; Y/hf/e from kk
    {
        int Y = kk >> 4, hf = (kk >> 3) & 1, e = kk & 7;
        size_t vbase = ((size_t)((b * NT + t) * 2 + Y) * 2 + (og >> 3)) * 512
                     + hf * 256 + e;
        #pragma unroll
        for (int j = 0; j < OG; ++j)
            Vf[vbase + ((og & 7) * 4 + j) * 8] = f2bf_rne(av[j]);
    }
}

// ---------------- flash attention pass 1: MFMA, pair-ILP (R15-proven structure) ----------------
__global__ __launch_bounds__(256, 4) void attn_pass1_mfma(
        const unsigned short* __restrict__ Qfh,
        const unsigned short* __restrict__ Kfh,
        const unsigned short* __restrict__ Vf,
        float* __restrict__ pm, float* __restrict__ pl, float* __restrict__ pacc) {
    int bid   = blockIdx.x;
    int split = bid / (BB * QUADS);         // split-major: co-resident share K/V window
    int rem   = bid % (BB * QUADS);
    int b     = rem / QUADS;
    int quad  = rem % QUADS;
    int wave  = threadIdx.x >> 6;
    int lane  = threadIdx.x & 63;
    int col   = lane & 31;
    int half  = lane >> 5;
    int qt    = quad * 4 + wave;
    bool qvalid = qt < NT;
    int qtc   = qvalid ? qt : NT - 1;
    int bNT   = b * NT;

    int tstart = (split * NT) / SPLITS;
    int tend   = ((split + 1) * NT) / SPLITS;
    int nkt    = tend - tstart;             // 31 or 32
    int npair  = nkt >> 1;
    int odd    = nkt & 1;

    __shared__ __align__(16) char ldsbuf[2][16384];  // pair: [Kh0 4K|V0 4K|Kh1 4K|V1 4K]

    short8 qfh[4];
    {
        const unsigned short* qp = Qfh + (size_t)(bNT + qtc) * 2048 + lane * 8;
        #pragma unroll
        for (int c = 0; c < 4; ++c) qfh[c] = ld_frag(qp + c * 512);
    }

    int wo = wave * 1024;
    int go = wo + lane * 16;

    auto STAGET = [&](int bufi, int slot, int tg) {
        size_t tb = (size_t)(bNT + tg) * 2048;
        char* l = &ldsbuf[bufi][slot * 8192];
        gload_lds16((const char*)(Kfh + tb) + go, l + wo);
        gload_lds16((const char*)(Vf  + tb) + go, l + 4096 + wo);
    };

    f32x16 oacc0 = {};
    f32x16 oacc1 = {};
    float m = -3e38f, lsum = 0.f;

    // softmax + PV for one tile (per-tile max update; R15-verified)
    auto SM_PV = [&](const f32x16& s, const unsigned short* lv) {
        float a0 = fmaxf(fmaxf(s[0],  s[1]),  s[2]);
        float a1 = fmaxf(fmaxf(s[3],  s[4]),  s[5]);
        float a2 = fmaxf(fmaxf(s[6],  s[7]),  s[8]);
        float a3 = fmaxf(fmaxf(s[9],  s[10]), s[11]);
        float a4 = fmaxf(fmaxf(s[12], s[13]), s[14]);
        float tmax = fmaxf(fmaxf(fmaxf(a0, a1), a2), fmaxf(fmaxf(a3, a4), s[15]));
        tmax = fmaxf(tmax, __shfl_xor(tmax, 32, 64));
        if (__any(tmax > m + 11.5f)) {
            float newm  = fmaxf(m, tmax);
            float scale = exp2_fast(m - newm);
            lsum *= scale;
            #pragma unroll
            for (int r = 0; r < 16; ++r) { oacc0[r] *= scale; oacc1[r] *= scale; }
            m = newm;
        }
        short8 pf0, pf1;
        float ls;
        {
            float p[8];
            #pragma unroll
            for (int r = 0; r < 8; ++r) p[r] = exp2_fast(s[r] - m);
            ls = ((p[0] + p[1]) + (p[2] + p[3])) + ((p[4] + p[5]) + (p[6] + p[7]));
            unsigned W[4], X[4];
            #pragma unroll
            for (int j = 0; j < 4; ++j)
                asm("v_cvt_pk_bf16_f32 %0, %1, %2" : "=v"(W[j]) : "v"(p[2 * j]), "v"(p[2 * j + 1]));
            #pragma unroll
            for (int j = 0; j < 4; ++j) X[j] = (unsigned)__shfl_xor((int)W[j], 32, 64);
            uint4 u = half ? make_uint4(X[2], X[3], W[2], W[3])
                           : make_uint4(W[0], W[1], X[0], X[1]);
            pf0 = __builtin_bit_cast(short8, u);
        }
        {
            float p[8];
            #pragma unroll
            for (int r = 0; r < 8; ++r) p[r] = exp2_fast(s[r + 8] - m);
            ls += ((p[0] + p[1]) + (p[2] + p[3])) + ((p[4] + p[5]) + (p[6] + p[7]));
            unsigned W[4], X[4];
            #pragma unroll
            for (int j = 0; j < 4; ++j)
                asm("v_cvt_pk_bf16_f32 %0, %1, %2" : "=v"(W[j]) : "v"(p[2 * j]), "v"(p[2 * j + 1]));
            #pragma unroll
            for (int j = 0; j < 4; ++j) X[j] = (unsigned)__shfl_xor((int)W[j], 32, 64);
            uint4 u = half ? make_uint4(X[2], X[3], W[2], W[3])
                           : make_uint4(W[0], W[1], X[0], X[1]);
            pf1 = __builtin_bit_cast(short8, u);
        }
        lsum += ls;
        short8 v00 = ld_frag(lv + 0 * 512 + lane * 8);   // Y0 X0
        short8 v10 = ld_frag(lv + 1 * 512 + lane * 8);   // Y0 X1
        __builtin_amdgcn_s_setprio(1);
        oacc0 = __builtin_amdgcn_mfma_f32_32x32x16_bf16(v00, pf0, oacc0, 0, 0, 0);
        oacc1 = __builtin_amdgcn_mfma_f32_32x32x16_bf16(v10, pf0, oacc1, 0, 0, 0);
        __builtin_amdgcn_s_setprio(0);
        short8 v01 = ld_frag(lv + 2 * 512 + lane * 8);   // Y1 X0
        short8 v11 = ld_frag(lv + 3 * 512 + lane * 8);   // Y1 X1
        __builtin_amdgcn_s_setprio(1);
        oacc0 = __builtin_amdgcn_mfma_f32_32x32x16_bf16(v01, pf1, oacc0, 0, 0, 0);
        oacc1 = __builtin_amdgcn_mfma_f32_32x32x16_bf16(v11, pf1, oacc1, 0, 0, 0);
        __builtin_amdgcn_s_setprio(0);
    };

    STAGET(0, 0, tstart);
    STAGET(0, 1, tstart + 1);

    for (int p = 0; p < npair; ++p) {
        __syncthreads();             // drains own pair's stage; prev buffer now free
        int nb = (p + 1) & 1;
        if (p + 1 < npair) {
            STAGET(nb, 0, tstart + 2 * p + 2);
            STAGET(nb, 1, tstart + 2 * p + 3);
        } else if (odd) {
            STAGET(nb, 0, tstart + 2 * p + 2);
        }
        const unsigned short* base = (const unsigned short*)&ldsbuf[p & 1][0];
        const unsigned short* lk0 = base;
        const unsigned short* lv0 = base + 2048;
        const unsigned short* lk1 = base + 4096;
        const unsigned short* lv1 = base + 6144;

        f32x16 s0 = {}, s1 = {};
        __builtin_amdgcn_s_setprio(1);
        #pragma unroll
        for (int c = 0; c < 4; ++c) {
            short8 k0 = ld_frag(lk0 + c * 512 + lane * 8);
            s0 = __builtin_amdgcn_mfma_f32_32x32x16_bf16(k0, qfh[c], s0, 0, 0, 0);
        }
        #pragma unroll
        for (int c = 0; c < 4; ++c) {
            short8 k1 = ld_frag(lk1 + c * 512 + lane * 8);
            s1 = __builtin_amdgcn_mfma_f32_32x32x16_bf16(k1, qfh[c], s1, 0, 0, 0);
        }
        __builtin_amdgcn_s_setprio(0);

        SM_PV(s0, lv0);
        SM_PV(s1, lv1);
    }
    if (odd) {
        __syncthreads();
        const unsigned short* base = (const unsigned short*)&ldsbuf[npair & 1][0];
        f32x16 s0 = {};
        __builtin_amdgcn_s_setprio(1);
        #pragma unroll
        for (int c = 0; c < 4; ++c) {
            short8 k0 = ld_frag(base + c * 512 + lane * 8);
            s0 = __builtin_amdgcn_mfma_f32_32x32x16_bf16(k0, qfh[c], s0, 0, 0, 0);
        }
        __builtin_amdgcn_s_setprio(0);
        SM_PV(s0, base + 2048);
    }

    if (!qvalid) return;
    int q0 = qt * 32;
    float lfull = lsum + __shfl_xor(lsum, 32, 64);
    size_t base = (size_t)b * SPLITS + split;
    if (lane < 32) {
        pm[base * NSP + q0 + col] = m;     // log2-domain running max
        pl[base * NSP + q0 + col] = lfull;
    }
    float* pa = pacc + base * (size_t)(COUT * NSP) + q0 + col;
    #pragma unroll
    for (int r = 0; r < 16; ++r) {
        int crow = (r & 3) + 8 * (r >> 2) + 4 * half;
        pa[(size_t)crow * NSP]        = oacc0[r];
        pa[(size_t)(crow + 32) * NSP] = oacc1[r];
    }
}

// ---------------- combine split-K partials (log2-domain, float4-vectorized) ----------------
__global__ void attn_combine_k(const float* __restrict__ pm, const float* __restrict__ pl,
                               const float* __restrict__ pacc, float* __restrict__ out) {
    int idx = blockIdx.x * blockDim.x + threadIdx.x;   // over B*COUT*NSP/4
    const int N4 = NSP / 4;
    if (idx >= BB * COUT * N4) return;
    int n4 = idx % N4;
    int c  = (idx / N4) % COUT;
    int b  = idx / (N4 * COUT);
    int n  = n4 * 4;

    float4 M = make_float4(-1e30f, -1e30f, -1e30f, -1e30f);
    #pragma unroll
    for (int j = 0; j < SPLITS; ++j) {
        float4 v = *reinterpret_cast<const float4*>(&pm[((size_t)b * SPLITS + j) * NSP + n]);
        M.x = fmaxf(M.x, v.x); M.y = fmaxf(M.y, v.y);
        M.z = fmaxf(M.z, v.z); M.w = fmaxf(M.w, v.w);
    }
    float4 L = make_float4(0.f, 0.f, 0.f, 0.f);
    float4 O = make_float4(0.f, 0.f, 0.f, 0.f);
    #pragma unroll
    for (int j = 0; j < SPLITS; ++j) {
        size_t base = (size_t)b * SPLITS + j;
        float4 pmv = *reinterpret_cast<const float4*>(&pm[base * NSP + n]);
        float4 plv = *reinterpret_cast<const float4*>(&pl[base * NSP + n]);
        float4 pav = *reinterpret_cast<const float4*>(&pacc[(base * COUT + c) * NSP + n]);
        float4 wgt;
        wgt.x = exp2_fast(pmv.x - M.x); wgt.y = exp2_fast(pmv.y - M.y);
        wgt.z = exp2_fast(pmv.z - M.z); wgt.w = exp2_fast(pmv.w - M.w);
        L.x += plv.x * wgt.x; L.y += plv.y * wgt.y;
        L.z += plv.z * wgt.z; L.w += plv.w * wgt.w;
        O.x += pav.x * wgt.x; O.y += pav.y * wgt.y;
        O.z += pav.z * wgt.z; O.w += pav.w * wgt.w;
    }
    float4 r;
    r.x = O.x / L.x; r.y = O.y / L.y; r.z = O.z / L.z; r.w = O.w / L.w;
    *reinterpret_cast<float4*>(&out[((size_t)(b * COUT + c)) * NSP + n]) = r;
}

// ---------------- launch ----------------
extern "C" void kernel_launch(void* const* d_in, const int* in_sizes, int n_in,
                              void* d_out, int out_size, void* d_ws, size_t ws_size,
                              hipStream_t stream) {
    const float* x      = (const float*)d_in[0];
    const float* conv_w = (const float*)d_in[1];
    const float* conv_b = (const float*)d_in[2];
    const float* gamma  = (const float*)d_in[3];
    const float* beta   = (const float*)d_in[4];
    const float* wq     = (const float*)d_in[5];
    const float* bq     = (const float*)d_in[6];
    const float* wk     = (const float*)d_in[7];
    const float* bk     = (const float*)d_in[8];
    const float* wv     = (const float*)d_in[9];
    const float* bv     = (const float*)d_in[10];
    float* out = (float*)d_out;

    const int ELEMS = BB * COUT * NSP;      // 1,024,000
    char* w8 = (char*)d_ws;
    float*  y    = (float*)w8;                          // 4,096,000 B
    float2* part = (float2*)(w8 + 4096000);             // 128*32 float2 = 32,768 B
    unsigned short* Qfh = (unsigned short*)(w8 + 4128768);
    unsigned short* Kfh = Qfh + (size_t)ELEMS;          // each 2,048,000 B
    unsigned short* Vf  = Kfh + (size_t)ELEMS;
    float* pm   = (float*)(Vf + (size_t)ELEMS);
    float* pl   = pm + (size_t)BB * SPLITS * NSP;       // 512,000 B each
    float* pacc = pl + (size_t)BB * SPLITS * NSP;       // 32,768,000 B
    // xpad aliases pacc: xpad live only before conv3d_k; pacc only after qkv_k
    float* xpad = pacc;                                 // needs 2,725,888 B

    pad_k<<<(BB * CIN * PSP + 255) / 256, 256, 0, stream>>>(x, xpad);
    conv3d_k<<<BB * 16 * 32, 256, 0, stream>>>(xpad, conv_w, conv_b, y, part);
    qkv_k<<<BB * 16 * 32, 256, 0, stream>>>(y, part, gamma, beta,
                                            wq, bq, wk, bk, wv, bv,
                                            Qfh, Kfh, Vf);
    attn_pass1_mfma<<<SPLITS * BB * QUADS, 256, 0, stream>>>(Qfh, Kfh, Vf,
                                                             pm, pl, pacc);
    attn_combine_k<<<(BB * COUT * (NSP / 4) + 255) / 256, 256, 0, stream>>>(pm, pl, pacc, out);
}